// Round 1
// baseline (332.264 us; speedup 1.0000x reference)
//
#include <hip/hip_runtime.h>

// Smallfry decode: out[b,s,:] = concat_{blk<128} codebook[codes[input_ids[b,s], blk], :4]
// Shapes: input_ids [32,4096] i32, codes [100000,128] i32, codebook [256,4] f32,
// out [32,4096,512] f32.

#define NUM_BLOCKS 128
#define NUM_CODES  256
#define NTOK       (32 * 4096)

__global__ __launch_bounds__(256) void smallfry_decode_kernel(
    const int* __restrict__ input_ids,
    const int* __restrict__ codes,
    const float4* __restrict__ codebook,   // 256 rows, each one float4
    float4* __restrict__ out)              // NTOK * 128 float4s
{
    __shared__ float4 cb[NUM_CODES];       // 4 KiB codebook in LDS
    if (threadIdx.x < NUM_CODES) {
        cb[threadIdx.x] = codebook[threadIdx.x];
    }
    __syncthreads();

    const int gtid   = blockIdx.x * blockDim.x + threadIdx.x;
    const int lane   = gtid & 63;
    const int wave   = gtid >> 6;
    const int nwaves = (gridDim.x * blockDim.x) >> 6;

    // One wave per token; lane i handles blocks 2i and 2i+1.
    for (int token = wave; token < NTOK; token += nwaves) {
        const int row = input_ids[token];               // same addr across wave -> broadcast
        // Coalesced: wave reads the whole 512B code row; lane i gets int2 at 8*i bytes.
        const int2* crow = reinterpret_cast<const int2*>(codes + (long long)row * NUM_BLOCKS);
        const int2 cc = crow[lane];

        const float4 v0 = cb[cc.x];
        const float4 v1 = cb[cc.y];

        // Coalesced: wave writes the full 2KiB output row; lane i writes bytes [32i, 32i+32).
        float4* orow = out + (long long)token * (NUM_BLOCKS) + lane * 2;
        orow[0] = v0;
        orow[1] = v1;
    }
}

extern "C" void kernel_launch(void* const* d_in, const int* in_sizes, int n_in,
                              void* d_out, int out_size, void* d_ws, size_t ws_size,
                              hipStream_t stream) {
    const int*    input_ids = (const int*)d_in[0];
    const int*    codes     = (const int*)d_in[1];
    const float4* codebook  = (const float4*)d_in[2];
    float4*       out       = (float4*)d_out;

    const int block = 256;
    const int grid  = 4096;   // 16384 waves, grid-stride over 131072 tokens
    smallfry_decode_kernel<<<grid, block, 0, stream>>>(input_ids, codes, codebook, out);
}

// Round 3
// 307.824 us; speedup vs baseline: 1.0794x; 1.0794x over previous
//
#include <hip/hip_runtime.h>

// Smallfry decode: out[b,s,:] = concat_{blk<128} codebook[codes[input_ids[b,s], blk], :4]
// input_ids [32,4096] i32, codes [100000,128] i32, codebook [256,4] f32,
// out [32,4096,512] f32 (= [NTOK,128] float4).

#define NUM_BLOCKS 128
#define NUM_CODES  256
#define NTOK       (32 * 4096)
#define TOK_PER_WAVE 16

typedef float f32x4 __attribute__((ext_vector_type(4)));

__global__ __launch_bounds__(256, 8) void smallfry_decode_kernel(
    const int* __restrict__ input_ids,
    const int* __restrict__ codes,
    const f32x4* __restrict__ codebook,
    f32x4* __restrict__ out)
{
    __shared__ f32x4 cb[NUM_CODES];        // 4 KiB codebook in LDS
    if (threadIdx.x < NUM_CODES) {
        cb[threadIdx.x] = codebook[threadIdx.x];
    }
    __syncthreads();

    const int gtid = blockIdx.x * blockDim.x + threadIdx.x;
    const int lane = gtid & 63;
    const int wave = gtid >> 6;            // 8192 waves, one 16-token group each

    const int base = wave * TOK_PER_WAVE;  // exactly covers NTOK = 8192*16

    // One coalesced load fetches all 16 token ids for this wave (lanes 0..15).
    int tok_id = 0;
    if (lane < TOK_PER_WAVE) tok_id = input_ids[base + lane];

#pragma unroll 4
    for (int t = 0; t < TOK_PER_WAVE; ++t) {
        const int row = __shfl(tok_id, t);             // uniform t -> v_readlane, row in SGPR
        const int* crow = codes + (long long)row * NUM_BLOCKS;
        // Two fully-coalesced 256B dword loads: lane gets blocks `lane` and `lane+64`.
        const int c0 = crow[lane];
        const int c1 = crow[lane + 64];

        const f32x4 v0 = cb[c0];
        const f32x4 v1 = cb[c1];

        // Each store instruction covers a fully contiguous 1 KiB; nontemporal to
        // keep L2 for the codes table (output is write-once streaming).
        f32x4* orow = out + (size_t)(base + t) * NUM_BLOCKS;
        __builtin_nontemporal_store(v0, &orow[lane]);
        __builtin_nontemporal_store(v1, &orow[lane + 64]);
    }
}

extern "C" void kernel_launch(void* const* d_in, const int* in_sizes, int n_in,
                              void* d_out, int out_size, void* d_ws, size_t ws_size,
                              hipStream_t stream) {
    const int*   input_ids = (const int*)d_in[0];
    const int*   codes     = (const int*)d_in[1];
    const f32x4* codebook  = (const f32x4*)d_in[2];
    f32x4*       out       = (f32x4*)d_out;

    const int block = 256;                         // 4 waves/block
    const int grid  = (NTOK / TOK_PER_WAVE) / 4;   // 2048 blocks -> 8192 waves
    smallfry_decode_kernel<<<grid, block, 0, stream>>>(input_ids, codes, codebook, out);
}

// Round 5
// 304.379 us; speedup vs baseline: 1.0916x; 1.0113x over previous
//
#include <hip/hip_runtime.h>

// Smallfry decode: out[b,s,:] = concat_{blk<128} codebook[codes[input_ids[b,s], blk], :4]
// input_ids [32,4096] i32, codes [100000,128] i32, codebook [256,4] f32,
// out [32,4096,512] f32 (= [NTOK,128] float4).

#define NUM_BLOCKS 128
#define NUM_CODES  256
#define NTOK       (32 * 4096)
#define TOK_PER_WAVE 16

typedef float f32x4 __attribute__((ext_vector_type(4)));

__global__ __launch_bounds__(256, 8) void smallfry_decode_kernel(
    const int* __restrict__ input_ids,
    const int* __restrict__ codes,
    const f32x4* __restrict__ codebook,
    f32x4* __restrict__ out)
{
    __shared__ f32x4 cb[NUM_CODES];        // 4 KiB codebook in LDS
    if (threadIdx.x < NUM_CODES) {
        cb[threadIdx.x] = codebook[threadIdx.x];
    }
    __syncthreads();

    const int gtid = blockIdx.x * blockDim.x + threadIdx.x;
    const int lane = gtid & 63;
    const int wave = gtid >> 6;            // 8192 waves, one 16-token group each
    const int base = wave * TOK_PER_WAVE;  // exactly covers NTOK = 8192*16

    // One coalesced load fetches all 16 token ids for this wave (lanes 0..15).
    int tok_id = 0;
    if (lane < TOK_PER_WAVE) tok_id = input_ids[base + lane];

    // Two phases of 8 tokens, fully unrolled: 16 code loads issued back-to-back
    // (max MLP), then LDS lookups + contiguous nontemporal stores.
#pragma unroll
    for (int g = 0; g < 2; ++g) {
        int c0[8], c1[8];
#pragma unroll
        for (int t = 0; t < 8; ++t) {
            const int row = __shfl(tok_id, g * 8 + t);   // uniform -> readlane/SGPR base
            const int* crow = codes + (long long)row * NUM_BLOCKS;
            c0[t] = crow[lane];          // coalesced 256B: blocks [0,64)
            c1[t] = crow[lane + 64];     // coalesced 256B: blocks [64,128)
        }
#pragma unroll
        for (int t = 0; t < 8; ++t) {
            const f32x4 v0 = cb[c0[t]];
            const f32x4 v1 = cb[c1[t]];
            // Each store instruction covers a fully contiguous 1 KiB of the row.
            f32x4* orow = out + (size_t)(base + g * 8 + t) * NUM_BLOCKS;
            __builtin_nontemporal_store(v0, &orow[lane]);
            __builtin_nontemporal_store(v1, &orow[lane + 64]);
        }
    }
}

extern "C" void kernel_launch(void* const* d_in, const int* in_sizes, int n_in,
                              void* d_out, int out_size, void* d_ws, size_t ws_size,
                              hipStream_t stream) {
    const int*   input_ids = (const int*)d_in[0];
    const int*   codes     = (const int*)d_in[1];
    const f32x4* codebook  = (const f32x4*)d_in[2];
    f32x4*       out       = (f32x4*)d_out;

    const int block = 256;                         // 4 waves/block
    const int grid  = (NTOK / TOK_PER_WAVE) / 4;   // 2048 blocks -> 8192 waves
    smallfry_decode_kernel<<<grid, block, 0, stream>>>(input_ids, codes, codebook, out);
}